// Round 4
// baseline (220.102 us; speedup 1.0000x reference)
//
#include <hip/hip_runtime.h>
#include <math.h>

#define DELTA_V 0.5f
#define DELTA_D 3.0f
#define P_REG   0.001f

#define TPB    256
#define BIN_B  64    // blocks per binary slice (6 MB -> 96 KB/block)
#define INST_B 128   // blocks per instance slice (12 MB -> 96 KB/block)
#define NBLK   (4 * BIN_B + 4 * INST_B)   // 768 blocks = 3/CU, co-resident
#define NVMAX  36

// workspace layout (float offsets). counters zeroed by 64-B memset; everything
// else is written before it is read.
#define CTR_OFF  0                              // 16 ints: [0..7] slice ctrs, [8] global ctr
#define P1_OFF   16                             // [8][INST_B][NVMAX] pass1 partials
#define CNT_OFF  (P1_OFF + 8 * INST_B * NVMAX)  // [8][6]
#define MEAN_OFF (CNT_OFF + 48)                 // [8][30]
#define LDR_OFF  (MEAN_OFF + 240)               // [8]
#define P2_OFF   (LDR_OFF + 8)                  // [8][INST_B][6] pass2 partials

// ---------------- Pass 1 body: per-label counts and sums ----------------
template<int K, int D>
__device__ void pass1_body(const float* __restrict__ pred,   // [D][MN] this batch
                           const int*  __restrict__ labels,  // [MN]
                           float* __restrict__ partials,     // this block's [NVMAX] slot
                           int n4, int j, int NB, float (*lredW)[NVMAX]) {
    constexpr int NV = K * (D + 1);
    const float4* pred4 = (const float4*)pred;
    const int4*   lab4  = (const int4*)labels;

    float acc[K][D + 1];
    #pragma unroll
    for (int k = 0; k < K; ++k)
        #pragma unroll
        for (int jj = 0; jj <= D; ++jj) acc[k][jj] = 0.f;

    const int idx0   = j * TPB + threadIdx.x;
    const int stride = NB * TPB;
    for (int i = idx0; i < n4; i += stride) {
        int4 lv = lab4[i];
        int labs[4] = {lv.x, lv.y, lv.z, lv.w};
        float4 xv[D];
        #pragma unroll
        for (int d = 0; d < D; ++d) xv[d] = pred4[(size_t)d * n4 + i];
        const float* xs = (const float*)&xv[0];   // xs[d*4 + c]
        #pragma unroll
        for (int c = 0; c < 4; ++c) {
            const int lab = labs[c];
            #pragma unroll
            for (int k = 0; k < K; ++k) {
                const float ind = (lab == k) ? 1.f : 0.f;
                acc[k][D] += ind;
                #pragma unroll
                for (int d = 0; d < D; ++d)
                    acc[k][d] = fmaf(ind, xs[d * 4 + c], acc[k][d]);
            }
        }
    }

    const int wave = threadIdx.x >> 6, lane = threadIdx.x & 63;
    #pragma unroll
    for (int k = 0; k < K; ++k) {
        #pragma unroll
        for (int jj = 0; jj <= D; ++jj) {
            float v = acc[k][jj];
            for (int off = 32; off > 0; off >>= 1) v += __shfl_down(v, off);
            if (lane == 0) lredW[wave][k * (D + 1) + jj] = v;
        }
    }
    __syncthreads();
    if (threadIdx.x < NV) {
        const int t = threadIdx.x;
        partials[t] = lredW[0][t] + lredW[1][t] + lredW[2][t] + lredW[3][t];
    }
}

__device__ __forceinline__ void block_map(int bx, int& s, int& j, int& NB) {
    if (bx < 4 * BIN_B) { s = bx / BIN_B; j = bx % BIN_B; NB = BIN_B; }
    else { int q = bx - 4 * BIN_B; s = 4 + q / INST_B; j = q % INST_B; NB = INST_B; }
}

// ---------------- Kernel 1: pass1 + last-block-per-slice computes means/ldr ----------------
__global__ __launch_bounds__(TPB)
void k1(const float* __restrict__ bl, const int* __restrict__ bL,
        const float* __restrict__ il, const int* __restrict__ iL,
        float* __restrict__ ws, int MN) {
    int s, j, NB;
    block_map(blockIdx.x, s, j, NB);
    const int b = s & 3;
    const int n4 = MN >> 2;
    __shared__ float lredW[4][NVMAX];
    float* partials = ws + P1_OFF + (size_t)(s * INST_B + j) * NVMAX;
    if (s < 4) pass1_body<2, 2>(bl + (size_t)b * 2 * MN, bL + (size_t)b * MN, partials, n4, j, NB, lredW);
    else       pass1_body<6, 5>(il + (size_t)b * 5 * MN, iL + (size_t)b * MN, partials, n4, j, NB, lredW);
    __syncthreads();

    __shared__ int amLast;
    if (threadIdx.x == 0) {
        __threadfence();   // release: partials visible device-wide before ctr bump
        int* ctr = (int*)ws + CTR_OFF + s;
        int old = atomicAdd(ctr, 1);   // device-scope by default on gfx950
        amLast = (old == NB - 1);
    }
    __syncthreads();
    if (!amLast) return;
    __threadfence();   // acquire: see all blocks' partials

    const int K = (s < 4) ? 2 : 6, D = (s < 4) ? 2 : 5;
    const int NV = K * (D + 1);
    __shared__ float tot[NVMAX];
    __shared__ float muS[30];
    __shared__ float cntS[6];
    const int t = threadIdx.x;
    if (t < NV) {
        const float* P = ws + P1_OFF + (size_t)s * INST_B * NVMAX;
        float v = 0.f;
        for (int jj = 0; jj < NB; ++jj) v += P[jj * NVMAX + t];
        tot[t] = v;
        const int k = t / (D + 1), r = t % (D + 1);
        if (r == D) { cntS[k] = v; ws[CNT_OFF + s * 6 + k] = v; }
    }
    __syncthreads();
    if (t < NV) {
        const int k = t / (D + 1), r = t % (D + 1);
        if (r < D) {
            const float m = tot[t] / cntS[k];
            muS[k * D + r] = m;
            ws[MEAN_OFF + s * 30 + k * D + r] = m;
        }
    }
    __syncthreads();
    if (t == 0) {
        float l_dist = 0.f, l_reg = 0.f;
        for (int i = 0; i < K; ++i) {
            float n2 = 0.f;
            for (int d = 0; d < D; ++d) n2 += muS[i * D + d] * muS[i * D + d];
            l_reg += sqrtf(n2);
            for (int jj = 0; jj < K; ++jj) {
                if (i == jj) continue;
                float sq = 0.f;
                for (int d = 0; d < D; ++d) { const float df = muS[i * D + d] - muS[jj * D + d]; sq += df * df; }
                const float dn = fmaxf(2.f * DELTA_D - sqrtf(sq), 0.f);
                l_dist += dn * dn;
            }
        }
        l_dist /= (float)(K * (K - 1));
        l_reg  /= (float)K;
        ws[LDR_OFF + s] = l_dist + P_REG * l_reg;
        __threadfence();   // make means/ldr/cnt visible before k2 consumes them
    }
}

// ---------------- Pass 2 body: hinged variance ----------------
template<int K, int D>
__device__ void pass2_body(const float* __restrict__ pred,
                           const int*  __restrict__ labels,
                           const float* __restrict__ means,   // [K*D]
                           float* __restrict__ partials,      // this block's [6] slot
                           int n4, int j, int NB, float* mu, float (*lredW)[6]) {
    if (threadIdx.x < K * D) mu[threadIdx.x] = means[threadIdx.x];
    __syncthreads();

    const float4* pred4 = (const float4*)pred;
    const int4*   lab4  = (const int4*)labels;

    float acc[K];
    #pragma unroll
    for (int k = 0; k < K; ++k) acc[k] = 0.f;

    const int idx0   = j * TPB + threadIdx.x;
    const int stride = NB * TPB;
    for (int i = idx0; i < n4; i += stride) {
        int4 lv = lab4[i];
        int labs[4] = {lv.x, lv.y, lv.z, lv.w};
        float4 xv[D];
        #pragma unroll
        for (int d = 0; d < D; ++d) xv[d] = pred4[(size_t)d * n4 + i];
        const float* xs = (const float*)&xv[0];
        #pragma unroll
        for (int c = 0; c < 4; ++c) {
            const int lab = labs[c];
            float sq = 0.f;
            #pragma unroll
            for (int d = 0; d < D; ++d) {
                const float df = mu[lab * D + d] - xs[d * 4 + c];
                sq = fmaf(df, df, sq);
            }
            const float h = fmaxf(sqrtf(sq) - DELTA_V, 0.f);
            const float h2 = h * h;
            #pragma unroll
            for (int k = 0; k < K; ++k)
                acc[k] += (lab == k) ? h2 : 0.f;
        }
    }

    const int wave = threadIdx.x >> 6, lane = threadIdx.x & 63;
    #pragma unroll
    for (int k = 0; k < K; ++k) {
        float v = acc[k];
        for (int off = 32; off > 0; off >>= 1) v += __shfl_down(v, off);
        if (lane == 0) lredW[wave][k] = v;
    }
    __syncthreads();
    if (threadIdx.x < K) {
        const int t = threadIdx.x;
        partials[t] = lredW[0][t] + lredW[1][t] + lredW[2][t] + lredW[3][t];
    }
}

// ---------------- Kernel 2: pass2 + global last block folds outputs ----------------
__global__ __launch_bounds__(TPB)
void k2(const float* __restrict__ bl, const int* __restrict__ bL,
        const float* __restrict__ il, const int* __restrict__ iL,
        float* __restrict__ ws, float* __restrict__ out, int MN) {
    int s, j, NB;
    block_map(blockIdx.x, s, j, NB);
    const int b = s & 3;
    const int n4 = MN >> 2;
    __shared__ float mu[30];
    __shared__ float lredW[4][6];
    const float* means = ws + MEAN_OFF + s * 30;
    float* partials = ws + P2_OFF + (size_t)(s * INST_B + j) * 6;
    if (s < 4) pass2_body<2, 2>(bl + (size_t)b * 2 * MN, bL + (size_t)b * MN, means, partials, n4, j, NB, mu, lredW);
    else       pass2_body<6, 5>(il + (size_t)b * 5 * MN, iL + (size_t)b * MN, means, partials, n4, j, NB, mu, lredW);
    __syncthreads();

    __shared__ int amLast;
    if (threadIdx.x == 0) {
        __threadfence();
        int* ctr = (int*)ws + CTR_OFF + 8;
        int old = atomicAdd(ctr, 1);
        amLast = (old == NBLK - 1);
    }
    __syncthreads();
    if (!amLast) return;
    __threadfence();

    // fold: contrib[s2][k] = sum_j P2[s2][j][k] / cnt[s2][k]
    __shared__ float contrib[48];
    const int t = threadIdx.x;
    if (t < 48) {
        const int s2 = t / 6, k = t % 6;
        const int Ks = (s2 < 4) ? 2 : 6;
        const int NBs = (s2 < 4) ? BIN_B : INST_B;
        float c = 0.f;
        if (k < Ks) {
            const float* P = ws + P2_OFF + (size_t)s2 * INST_B * 6;
            float v = 0.f;
            for (int jj = 0; jj < NBs; ++jj) v += P[jj * 6 + k];
            c = v / ws[CNT_OFF + s2 * 6 + k];
        }
        contrib[t] = c;
    }
    __syncthreads();
    if (t == 0) {
        float totB = 0.f, totI = 0.f;
        for (int s2 = 0; s2 < 8; ++s2) {
            const int Ks = (s2 < 4) ? 2 : 6;
            float lv = 0.f;
            for (int k = 0; k < Ks; ++k) lv += contrib[s2 * 6 + k];
            lv /= (float)Ks;
            const float loss = lv + ws[LDR_OFF + s2];
            if (s2 < 4) totB += loss; else totI += loss;
        }
        out[0] = totB * 0.25f;
        out[1] = totI * 0.25f;
    }
}

extern "C" void kernel_launch(void* const* d_in, const int* in_sizes, int n_in,
                              void* d_out, int out_size, void* d_ws, size_t ws_size,
                              hipStream_t stream) {
    const float* bin_logits  = (const float*)d_in[0];
    const int*   bin_labels  = (const int*)d_in[1];
    const float* inst_logits = (const float*)d_in[2];
    const int*   inst_labels = (const int*)d_in[3];
    float* ws  = (float*)d_ws;
    float* out = (float*)d_out;

    const int B  = 4;
    const int MN = in_sizes[1] / B;   // 524288

    (void)hipMemsetAsync(d_ws, 0, 64, stream);   // zero the 16 counters only
    k1<<<NBLK, TPB, 0, stream>>>(bin_logits, bin_labels, inst_logits, inst_labels, ws, MN);
    k2<<<NBLK, TPB, 0, stream>>>(bin_logits, bin_labels, inst_logits, inst_labels, ws, out, MN);
}